// Round 3
// baseline (120.962 us; speedup 1.0000x reference)
//
#include <hip/hip_runtime.h>

#define IN_DIM  4096
#define OUT_DIM 11008
#define NSUB    1376
#define KSQ     256
#define DSUB    8
#define BATCH   32

#define DTILE   8                    // subspaces per block -> N tile = 64
#define NTILE   64
#define KC      128                  // k elements staged per chunk
#define KSPLIT  4                    // k-blocks in grid
#define KPB     (IN_DIM / KSPLIT)    // 1024 k per block
#define NCHUNK  (KPB / KC)           // 8 chunks per block
#define NBLK    (OUT_DIM / NTILE)    // 172

typedef unsigned short ushort_t;
typedef unsigned int   uint_t;
typedef __attribute__((ext_vector_type(8))) short bf16x8;
typedef __attribute__((ext_vector_type(4))) float f32x4;

// LDS strides (elements). 136 = 68 dwords (≡4 mod 32 banks): balanced b128 access.
#define SW_STRIDE 136
#define SX_STRIDE 136
#define SI_STRIDE 132

// workspace layout
#define VEC_N   (NSUB * KSQ * DSUB)          // 2818048 floats
#define XBF_OFF 5636096                      // bytes: VEC_N * 2
#define PREP_V  (VEC_N / 2)                  // 1409024 uint (2 bf16 each)
#define PREP_X  (BATCH * IN_DIM / 2)         // 65536
#define PREP_O  (BATCH * OUT_DIM)            // 352256
#define PREP_N  (PREP_V + PREP_X + PREP_O)   // 1826816 = 7136 * 256

__device__ __forceinline__ ushort_t f2bf(float f) {
    union { float f; uint_t u; } a; a.f = f;
    uint_t u = a.u;
    u += 0x7fffu + ((u >> 16) & 1u);   // round-to-nearest-even
    return (ushort_t)(u >> 16);
}

__global__ __launch_bounds__(256) void pq_prep(
    const float* __restrict__ x, const float* __restrict__ vecs,
    const float* __restrict__ bias,
    uint_t* __restrict__ vbf, uint_t* __restrict__ xbf, float* __restrict__ out)
{
    int tid = blockIdx.x * 256 + threadIdx.x;
    if (tid < PREP_V) {
        float2 v = ((const float2*)vecs)[tid];
        vbf[tid] = (uint_t)f2bf(v.x) | ((uint_t)f2bf(v.y) << 16);
    } else if (tid < PREP_V + PREP_X) {
        int i = tid - PREP_V;
        float2 v = ((const float2*)x)[i];
        xbf[i] = (uint_t)f2bf(v.x) | ((uint_t)f2bf(v.y) << 16);
    } else {
        int i = tid - (PREP_V + PREP_X);
        out[i] = bias[i % OUT_DIM];
    }
}

__global__ __launch_bounds__(256) void pq_main(
    const ushort_t* __restrict__ xbf, const uint4* __restrict__ vbf,
    const int* __restrict__ idx, float* __restrict__ out)
{
    __shared__ uint4    sCB[DTILE * KSQ];       // 32 KB: bf16 codebooks [d][256]
    __shared__ ushort_t sW[NTILE * SW_STRIDE];  // 17.4 KB: W^T tile [n][k]
    __shared__ ushort_t sX[BATCH * SX_STRIDE];  // 8.7 KB: x tile [m][k]
    __shared__ int      sI[DTILE * SI_STRIDE];  // 4.2 KB: idx tile [d][i]

    const int t    = threadIdx.x;
    const int nblk = blockIdx.x;        // 0..171
    const int kblk = blockIdx.y;        // 0..3
    const int d0   = nblk * DTILE;
    const int kbase = kblk * KPB;

    const int wave = t >> 6;
    const int lane = t & 63;
    const int l15  = lane & 15;
    const int l4   = lane >> 4;

    const int gd = t >> 5;              // gather: subspace 0..7
    const int go = t & 31;              // gather: k-quad 0..31

    const int ii0 = t >> 1;             // idx load: row 0..127
    const int g0  = t & 1;              // idx load: int4-group 0..1

    f32x4 acc[2];
    acc[0] = (f32x4)0.0f;
    acc[1] = (f32x4)0.0f;

    // --- stage this block's 8 sub-codebooks into LDS (coalesced, 32 KB)
    {
        const uint4* vb = vbf + (size_t)d0 * KSQ;
        #pragma unroll
        for (int p = 0; p < 8; ++p)
            sCB[p * 256 + t] = vb[p * 256 + t];
    }

    // --- prologue: prefetch chunk 0's idx + x into registers (coalesced)
    int4  ireg;
    uint4 xreg[2];
    ireg = *(const int4*)&idx[(size_t)(kbase + ii0) * NSUB + d0 + g0 * 4];
    #pragma unroll
    for (int p = 0; p < 2; ++p) {
        int f = p * 256 + t, b = f >> 4, qx = f & 15;
        xreg[p] = ((const uint4*)xbf)[b * (IN_DIM / 8) + kbase / 8 + qx];
    }

    for (int c = 0; c < NCHUNK; ++c) {
        __syncthreads();   // previous chunk's LDS frag reads done before restage

        // --- commit prefetched regs into LDS (idx transposed to [d][i])
        sI[(g0 * 4 + 0) * SI_STRIDE + ii0] = ireg.x;
        sI[(g0 * 4 + 1) * SI_STRIDE + ii0] = ireg.y;
        sI[(g0 * 4 + 2) * SI_STRIDE + ii0] = ireg.z;
        sI[(g0 * 4 + 3) * SI_STRIDE + ii0] = ireg.w;
        #pragma unroll
        for (int p = 0; p < 2; ++p) {
            int f = p * 256 + t, b = f >> 4, qx = f & 15;
            *(uint4*)&sX[b * SX_STRIDE + qx * 8] = xreg[p];
        }

        // --- prefetch next chunk's idx + x (in flight across the barriers)
        if (c + 1 < NCHUNK) {
            const int i0n = kbase + (c + 1) * KC;
            ireg = *(const int4*)&idx[(size_t)(i0n + ii0) * NSUB + d0 + g0 * 4];
            #pragma unroll
            for (int p = 0; p < 2; ++p) {
                int f = p * 256 + t, b = f >> 4, qx = f & 15;
                xreg[p] = ((const uint4*)xbf)[b * (IN_DIM / 8) + i0n / 8 + qx];
            }
        }
        __syncthreads();

        // --- gather 4 codewords (4 consecutive k, one d) from LDS codebook
        int4 kk = *(const int4*)&sI[gd * SI_STRIDE + go * 4];
        uint4 q0 = sCB[gd * KSQ + kk.x];
        uint4 q1 = sCB[gd * KSQ + kk.y];
        uint4 q2 = sCB[gd * KSQ + kk.z];
        uint4 q3 = sCB[gd * KSQ + kk.w];

        // --- 4x8 bf16 transpose via v_perm, write k-contiguous b64s to sW[n][k]
        #pragma unroll
        for (int j = 0; j < 8; ++j) {
            const uint_t sel = (j & 1) ? 0x07060302u : 0x05040100u;
            const int cc = j >> 1;
            uint_t c0 = cc == 0 ? q0.x : cc == 1 ? q0.y : cc == 2 ? q0.z : q0.w;
            uint_t c1 = cc == 0 ? q1.x : cc == 1 ? q1.y : cc == 2 ? q1.z : q1.w;
            uint_t c2 = cc == 0 ? q2.x : cc == 1 ? q2.y : cc == 2 ? q2.z : q2.w;
            uint_t c3 = cc == 0 ? q3.x : cc == 1 ? q3.y : cc == 2 ? q3.z : q3.w;
            uint2 wv;
            wv.x = __builtin_amdgcn_perm(c1, c0, sel);
            wv.y = __builtin_amdgcn_perm(c3, c2, sel);
            *(uint2*)&sW[(gd * 8 + j) * SW_STRIDE + go * 4] = wv;
        }
        __syncthreads();

        // --- MFMA over this chunk: wave owns 16 cols, full M=32
        #pragma unroll
        for (int kq = 0; kq < KC / 32; ++kq) {
            bf16x8 A0 = *(const bf16x8*)&sX[(l15) * SX_STRIDE + kq * 32 + l4 * 8];
            bf16x8 A1 = *(const bf16x8*)&sX[(16 + l15) * SX_STRIDE + kq * 32 + l4 * 8];
            bf16x8 B  = *(const bf16x8*)&sW[(wave * 16 + l15) * SW_STRIDE + kq * 32 + l4 * 8];
            acc[0] = __builtin_amdgcn_mfma_f32_16x16x32_bf16(A0, B, acc[0], 0, 0, 0);
            acc[1] = __builtin_amdgcn_mfma_f32_16x16x32_bf16(A1, B, acc[1], 0, 0, 0);
        }
    }

    // --- epilogue: accumulate into out (pre-initialized with bias); 4/address
    #pragma unroll
    for (int mt = 0; mt < 2; ++mt)
        #pragma unroll
        for (int r = 0; r < 4; ++r) {
            int row = mt * 16 + l4 * 4 + r;                 // batch
            int col = nblk * NTILE + wave * 16 + l15;       // out col
            atomicAdd(&out[(size_t)row * OUT_DIM + col], acc[mt][r]);
        }
}

extern "C" void kernel_launch(void* const* d_in, const int* in_sizes, int n_in,
                              void* d_out, int out_size, void* d_ws, size_t ws_size,
                              hipStream_t stream) {
    const float* x    = (const float*)d_in[0];
    const float* vecs = (const float*)d_in[1];
    const float* bias = (const float*)d_in[2];
    const int*   idx  = (const int*)d_in[3];
    float* out = (float*)d_out;

    uint_t* vbf = (uint_t*)d_ws;                           // 5.6 MB bf16 codebook
    uint_t* xbf = (uint_t*)((char*)d_ws + XBF_OFF);        // 256 KB bf16 x

    pq_prep<<<PREP_N / 256, 256, 0, stream>>>(x, vecs, bias, vbf, xbf, out);
    dim3 grid(NBLK, KSPLIT);
    pq_main<<<grid, 256, 0, stream>>>((const ushort_t*)xbf, (const uint4*)vbf,
                                      idx, out);
}